// Round 5
// baseline (349.187 us; speedup 1.0000x reference)
//
#include <hip/hip_runtime.h>
#include <math.h>

// Problem constants (fixed by the reference)
#define BB 256
#define TT 512
#define DD 128
#define HH 128
#define GG 512   // 4*H
#define OO 64

#define LOG2E    1.44269504088896340736f
#define TWOLOG2E 2.88539008177792681472f

typedef _Float16 half8 __attribute__((ext_vector_type(8)));
typedef float    f32x4 __attribute__((ext_vector_type(4)));

// ---------------------------------------------------------------------------
// Kernel 1 (fused): blocks [0,TT): xg; blocks [TT,TT+16): weight packing.
//
// PRESCALE: W_hh rows and xg are multiplied by log2e (gates i,f,o) or
// 2*log2e (gate g) at pack time, so every activation in the scan is a bare
// v_exp_f32 (=2^x) with sign/abs folded into input modifiers. c is kept in
// 2*log2e-scaled units (scale-invariant recurrence, see scan kernel).
//
// xg[t][j][gate]: input-gate contribution, PACKED per-hidden-index so a scan
// lane reads i,f,g,o as one 16-B vector. Only batch 255 matters:
// y.reshape(T,B,O)[-1] -> flat rows (b=255, t>=256); b=255's scan needs all t.
//
// wpack — R5 8-WAVE layout (derived 1:1 from the r3/r8-verified 4-wave map;
// only the row selection changed: row = gate*128 + jsel, jsel = w*16 + col):
//   wave w(0..7), gate gt(0..3), k-tile kt(0..3), lane l:
//   row = gt*128 + w*16 + (l&15); off = kt*32 + (l>>4)*8
//   dst = Wp[((w*16 + gt*4 + kt)*64 + l)*8 .. +8]
// ---------------------------------------------------------------------------
__global__ __launch_bounds__(512) void xgpack_kernel(
    const float* __restrict__ x,
    const float* __restrict__ W_ih,
    const float* __restrict__ b_ih,
    const float* __restrict__ b_hh,
    const float* __restrict__ W_hh,
    float* __restrict__ xg,
    _Float16* __restrict__ Wp)
{
    if (blockIdx.x >= TT) {   // ---- weight-packing blocks ----
        const int g = (blockIdx.x - TT) * 512 + threadIdx.x;  // 0..8191
        const int fid = g >> 6, l = g & 63;
        const int w = fid >> 4, rem = fid & 15, gt = rem >> 2, kt = rem & 3;
        const int quad = l >> 4, col = l & 15;
        const int row = gt * 128 + w * 16 + col;
        const int off = kt * 32 + quad * 8;
        const float ws = (gt == 2) ? TWOLOG2E : LOG2E;  // g-gate rows 2x
        const float* s = W_hh + row * HH + off;
        _Float16* d = Wp + (size_t)g * 8;
#pragma unroll
        for (int i = 0; i < 8; i++) d[i] = (_Float16)(s[i] * ws);
        return;
    }

    const int t = blockIdx.x;
    const int g = threadIdx.x;

    __shared__ __align__(16) float xs[DD];
    if (g < DD) xs[g] = x[(255 * TT + t) * DD + g];
    __syncthreads();

    const float4* __restrict__ wrow = (const float4*)(W_ih + g * DD);
    const float4* __restrict__ xv   = (const float4*)xs;

    float a0 = 0.f, a1 = 0.f, a2 = 0.f, a3 = 0.f;
#pragma unroll
    for (int i = 0; i < DD / 4; i += 4) {
        float4 w0 = wrow[i + 0], w1 = wrow[i + 1], w2 = wrow[i + 2], w3 = wrow[i + 3];
        float4 h0 = xv[i + 0],  h1 = xv[i + 1],  h2 = xv[i + 2],  h3 = xv[i + 3];
        a0 += w0.x * h0.x + w0.y * h0.y + w0.z * h0.z + w0.w * h0.w;
        a1 += w1.x * h1.x + w1.y * h1.y + w1.z * h1.z + w1.w * h1.w;
        a2 += w2.x * h2.x + w2.y * h2.y + w2.z * h2.z + w2.w * h2.w;
        a3 += w3.x * h3.x + w3.y * h3.y + w3.z * h3.z + w3.w * h3.w;
    }
    const float scale = ((g >> 7) == 2) ? TWOLOG2E : LOG2E;
    const float val = ((a0 + a1) + (a2 + a3) + b_ih[g] + b_hh[g]) * scale;
    xg[t * GG + (g & 127) * 4 + (g >> 7)] = val;   // packed [t][j][gate]
}

// ---------------------------------------------------------------------------
// Kernel 2: MFMA LSTM scan (batch 255). R5: 1 block, 512 threads = 8 WAVES.
//
// Theory: the step (963 cyc at R4) is serial-chain-bound; the largest
// controllable discrete term is per-wave MFMA issue (32 x ~5 = 160 cyc).
// 8-wave split: wave w owns hidden slice [16w,16w+16) for ALL 4 gates ->
// 4 chains x 4 k-tiles = 16 MFMA/wave (issue ~80). Also removes the sel
// cndmasks (lane's gate values are C0..C3[0] directly) and frees 64
// B-fragment VGPRs/wave. 2 waves/SIMD interleave their stall segments;
// pipe contention (2x ds_read instrs, 2x trans issue) should hide in the
// ~70%-stall shadows. r11's 8-wave loss was on the old xgc-staging
// structure (heavy LDS pipe traffic) -- that traffic is gone.
//
// Kept from R4 (each independently verified): exp2-prescaled weights,
// sign-folded fma tails, Z-seeded accumulators (laundered), xpf temp
// prefetch, LDS hs ring (no per-step global store -- vmcnt entanglement),
// RAW lgkmcnt(0)+s_barrier, one-time B-fragment launder.
// ---------------------------------------------------------------------------
__global__
__attribute__((amdgpu_flat_work_group_size(512, 512), amdgpu_waves_per_eu(2, 2)))
void scan_kernel(
    const _Float16* __restrict__ Wp,
    const float* __restrict__ xgp,
    float* __restrict__ hs)
{
    const int tid  = threadIdx.x;
    const int lane = tid & 63;
    const int w    = tid >> 6;        // wave id 0..7
    const int col  = lane & 15;
    const int quad = lane >> 4;
    const int jsel = w * 16 + col;    // hidden index this lane updates
    const int aoff = quad * 8;
    const bool wr  = (quad == 0);     // one writer per hidden index

    __shared__ __align__(16) _Float16 h_lds[2][HH];          // 512 B
    __shared__ __align__(16) float hs_l[BB * HH];            // 128 KB ring

    // ---- B-fragments: contiguous 16-B loads from the packed buffer ----
    // Bgt_kt: gate gt (0=i,1=f,2=g,3=o), k-tile kt
#define BLOADP(gt, kt) \
    half8 B##gt##_##kt = *(const half8*)(Wp + (((w * 16 + (gt) * 4 + (kt)) * 64 + lane) * 8));
#define FOR_KT(X, gt) X(gt, 0) X(gt, 1) X(gt, 2) X(gt, 3)
#define FOR_GT(X) FOR_KT(X, 0) FOR_KT(X, 1) FOR_KT(X, 2) FOR_KT(X, 3)
    FOR_GT(BLOADP)

    // ---- ONE-TIME launder: opaque-define the fragments (cannot be sunk) ----
    asm volatile("" : "+v"(B0_0), "+v"(B0_1), "+v"(B0_2), "+v"(B0_3),
                      "+v"(B1_0), "+v"(B1_1), "+v"(B1_2), "+v"(B1_3),
                      "+v"(B2_0), "+v"(B2_1), "+v"(B2_2), "+v"(B2_3),
                      "+v"(B3_0), "+v"(B3_1), "+v"(B3_2), "+v"(B3_3));

    if (tid < HH) h_lds[0][tid] = (_Float16)0.f;

    // persistent zero accumulator seed (4 VGPRs, laundered so it is never
    // rematerialized as per-step v_movs)
    f32x4 Z = {0.f, 0.f, 0.f, 0.f};
    asm volatile("" : "+v"(Z));

    // 2-deep register prefetch of the packed gate biases (16 B/lane)
    const float* __restrict__ xgl = xgp + jsel * 4;
    f32x4 xg0 = *(const f32x4*)(xgl + 0 * GG);
    f32x4 xg1 = *(const f32x4*)(xgl + 1 * GG);

    float c = 0.f;   // in 2*log2e-scaled units
    __syncthreads();   // one-time full barrier (drains prologue loads too)

#define MM(a, b, cc) __builtin_amdgcn_mfma_f32_16x16x32_f16((a), (b), (cc), 0, 0, 0)
#define STEP(par, XCUR) do {                                                            \
    const int t = t2 + (par);                                                           \
    f32x4 xpf = *(const f32x4*)(xgl + ((t + 2) & (TT - 1)) * GG);                       \
    const _Float16* hl = h_lds[(par)];                                                  \
    half8 A0 = *(const half8*)(hl +  0 + aoff);                                         \
    half8 A1 = *(const half8*)(hl + 32 + aoff);                                         \
    half8 A2 = *(const half8*)(hl + 64 + aoff);                                         \
    half8 A3 = *(const half8*)(hl + 96 + aoff);                                         \
    f32x4 C0, C1, C2, C3;                                                               \
    C0 = MM(A0, B0_0, Z);  C1 = MM(A0, B1_0, Z);                                        \
    C2 = MM(A0, B2_0, Z);  C3 = MM(A0, B3_0, Z);                                        \
    C0 = MM(A1, B0_1, C0); C1 = MM(A1, B1_1, C1);                                       \
    C2 = MM(A1, B2_1, C2); C3 = MM(A1, B3_1, C3);                                       \
    C0 = MM(A2, B0_2, C0); C1 = MM(A2, B1_2, C1);                                       \
    C2 = MM(A2, B2_2, C2); C3 = MM(A2, B3_2, C3);                                       \
    C0 = MM(A3, B0_3, C0); C1 = MM(A3, B1_3, C1);                                       \
    C2 = MM(A3, B2_3, C2); C3 = MM(A3, B3_3, C3);                                       \
    /* pre-activations (exp2-prescaled): pg by 2log2e, others by log2e */               \
    float pi = C0[0] + (XCUR).x;                                                        \
    float pf = C1[0] + (XCUR).y;                                                        \
    float pg = C2[0] + (XCUR).z;                                                        \
    float po = C3[0] + (XCUR).w;                                                        \
    float iv = __builtin_amdgcn_rcpf(1.0f + __builtin_amdgcn_exp2f(-pi));               \
    float fv = __builtin_amdgcn_rcpf(1.0f + __builtin_amdgcn_exp2f(-pf));               \
    float ov = __builtin_amdgcn_rcpf(1.0f + __builtin_amdgcn_exp2f(-po));               \
    float Eg = __builtin_amdgcn_exp2f(fabsf(pg));                                       \
    float rg = __builtin_amdgcn_rcpf(Eg + 1.0f);                                        \
    float T  = copysignf(TWOLOG2E, pg);                                                 \
    float gvs = fmaf(-2.0f * T, rg, T);  /* = 2log2e * tanh(raw_g) */                   \
    c = fmaf(fv, c, iv * gvs);           /* c stays in 2log2e-scaled units */           \
    float Ec = __builtin_amdgcn_exp2f(fabsf(c));                                        \
    float rc = __builtin_amdgcn_rcpf(Ec + 1.0f);                                        \
    float Ao = copysignf(ov, c);                                                        \
    float hval = fmaf(-2.0f * Ao, rc, Ao);                                              \
    if (wr) {                                                                           \
        h_lds[1 - (par)][jsel] = (_Float16)hval;                                        \
        hs_l[(t & (BB - 1)) * HH + jsel] = hval; /* LDS ring, same lgkm wait */         \
    }                                                                                   \
    asm volatile("s_waitcnt lgkmcnt(0)\n\ts_barrier" ::: "memory");                     \
    (XCUR) = xpf;                                                                       \
} while (0)

    for (int t2 = 0; t2 < TT; t2 += 2) {
        STEP(0, xg0);   // reads h_lds[0], writes h_lds[1]
        STEP(1, xg1);   // reads h_lds[1], writes h_lds[0]
    }
#undef STEP
#undef MM

    // dump hs ring (128 KB LDS -> global, coalesced); last STEP's
    // lgkmcnt(0)+barrier already made all hs_l writes visible
    const f32x4* s = (const f32x4*)hs_l;
    f32x4* d = (f32x4*)hs;
#pragma unroll 4
    for (int i = tid; i < BB * HH / 4; i += 512) d[i] = s[i];
}

// ---------------------------------------------------------------------------
// Kernel 3: out[r,:] = W2 @ (W1 @ hs[r] + b1) + b2  (no activation in ref)
// ---------------------------------------------------------------------------
__global__ __launch_bounds__(128) void mlp_kernel(
    const float* __restrict__ hs,
    const float* __restrict__ W1,
    const float* __restrict__ b1,
    const float* __restrict__ W2,
    const float* __restrict__ b2,
    float* __restrict__ out)
{
    const int r = blockIdx.x;
    const int j = threadIdx.x;

    __shared__ __align__(16) float hsh[HH];
    __shared__ __align__(16) float z[HH];

    hsh[j] = hs[r * HH + j];
    __syncthreads();

    {
        const float4* __restrict__ wrow = (const float4*)(W1 + j * HH);
        const float4* __restrict__ hv   = (const float4*)hsh;
        float acc = b1[j];
#pragma unroll
        for (int i = 0; i < 32; i++) {
            float4 ww = wrow[i], h = hv[i];
            acc += ww.x * h.x + ww.y * h.y + ww.z * h.z + ww.w * h.w;
        }
        z[j] = acc;
    }
    __syncthreads();

    if (j < OO) {
        const float4* __restrict__ wrow = (const float4*)(W2 + j * HH);
        const float4* __restrict__ zv   = (const float4*)z;
        float acc = b2[j];
#pragma unroll
        for (int i = 0; i < 32; i++) {
            float4 ww = wrow[i], zz = zv[i];
            acc += ww.x * zz.x + ww.y * zz.y + ww.z * zz.z + ww.w * zz.w;
        }
        out[r * OO + j] = acc;
    }
}

// ---------------------------------------------------------------------------
// Launch. Inputs: 0:x 1:W_ih 2:W_hh 3:b_ih 4:b_hh 5:W1 6:b1 7:W2 8:b2
// ws: xg packed (1 MB) | hs (128 KB) | Wp packed f16 frags (128 KB)
// ---------------------------------------------------------------------------
extern "C" void kernel_launch(void* const* d_in, const int* in_sizes, int n_in,
                              void* d_out, int out_size, void* d_ws, size_t ws_size,
                              hipStream_t stream) {
    const float* x    = (const float*)d_in[0];
    const float* W_ih = (const float*)d_in[1];
    const float* W_hh = (const float*)d_in[2];
    const float* b_ih = (const float*)d_in[3];
    const float* b_hh = (const float*)d_in[4];
    const float* W1   = (const float*)d_in[5];
    const float* b1   = (const float*)d_in[6];
    const float* W2   = (const float*)d_in[7];
    const float* b2   = (const float*)d_in[8];
    float* out = (float*)d_out;

    float*    xg = (float*)d_ws;                 // T*4H   = 262144 f32 (packed)
    float*    hs = xg + TT * GG;                 // 256*H  =  32768 f32
    _Float16* Wp = (_Float16*)(hs + BB * HH);    // 4H*H   =  65536 f16 (packed frags)

    xgpack_kernel<<<TT + 16, 512, 0, stream>>>(x, W_ih, b_ih, b_hh, W_hh, xg, Wp);
    scan_kernel<<<1, 512, 0, stream>>>(Wp, xg, hs);
    mlp_kernel<<<BB, 128, 0, stream>>>(hs, W1, b1, W2, b2, out);
}

// Round 6
// 331.064 us; speedup vs baseline: 1.0547x; 1.0547x over previous
//
#include <hip/hip_runtime.h>
#include <math.h>

// Problem constants (fixed by the reference)
#define BB 256
#define TT 512
#define DD 128
#define HH 128
#define GG 512   // 4*H
#define OO 64

#define LOG2E    1.44269504088896340736f
#define TWOLOG2E 2.88539008177792681472f

typedef _Float16 half8 __attribute__((ext_vector_type(8)));
typedef float    f32x4 __attribute__((ext_vector_type(4)));

// ---------------------------------------------------------------------------
// Kernel 1 (fused): blocks [0,TT): xg; blocks [TT,TT+16): weight packing.
//
// PRESCALE: W_hh rows and xg are multiplied by log2e (gates i,f,o) or
// 2*log2e (gate g) at pack time, so every activation in the scan is a bare
// v_exp_f32 (=2^x) with sign/abs folded into input modifiers. c is kept in
// 2*log2e-scaled units (scale-invariant recurrence, see scan kernel).
//
// xg[t][j][gate]: input-gate contribution, PACKED per-hidden-index so a scan
// lane reads i,f,g,o as one 16-B vector. Only batch 255 matters:
// y.reshape(T,B,O)[-1] -> flat rows (b=255, t>=256); b=255's scan needs all t.
//
// wpack (4-wave layout, r3/r8-verified fragment math):
//   wave w(0..3), n-tile nt(0..7), k-tile kt(0..3), lane l:
//   row = (nt>>1)*128 + (nt&1)*16 + w*32 + (l&15); off = kt*32 + (l>>4)*8
//   dst = Wp[((w*32 + nt*4 + kt)*64 + l)*8 .. +8]
// ---------------------------------------------------------------------------
__global__ __launch_bounds__(512) void xgpack_kernel(
    const float* __restrict__ x,
    const float* __restrict__ W_ih,
    const float* __restrict__ b_ih,
    const float* __restrict__ b_hh,
    const float* __restrict__ W_hh,
    float* __restrict__ xg,
    _Float16* __restrict__ Wp)
{
    if (blockIdx.x >= TT) {   // ---- weight-packing blocks ----
        const int g = (blockIdx.x - TT) * 512 + threadIdx.x;  // 0..8191
        const int fid = g >> 6, l = g & 63;
        const int w = fid >> 5, rem = fid & 31, nt = rem >> 2, kt = rem & 3;
        const int quad = l >> 4, col = l & 15;
        const int row = (nt >> 1) * 128 + (nt & 1) * 16 + w * 32 + col;
        const int off = kt * 32 + quad * 8;
        const float ws = ((row >> 7) == 2) ? TWOLOG2E : LOG2E;  // g-gate rows 2x
        const float* s = W_hh + row * HH + off;
        _Float16* d = Wp + (size_t)g * 8;
#pragma unroll
        for (int i = 0; i < 8; i++) d[i] = (_Float16)(s[i] * ws);
        return;
    }

    const int t = blockIdx.x;
    const int g = threadIdx.x;

    __shared__ __align__(16) float xs[DD];
    if (g < DD) xs[g] = x[(255 * TT + t) * DD + g];
    __syncthreads();

    const float4* __restrict__ wrow = (const float4*)(W_ih + g * DD);
    const float4* __restrict__ xv   = (const float4*)xs;

    float a0 = 0.f, a1 = 0.f, a2 = 0.f, a3 = 0.f;
#pragma unroll
    for (int i = 0; i < DD / 4; i += 4) {
        float4 w0 = wrow[i + 0], w1 = wrow[i + 1], w2 = wrow[i + 2], w3 = wrow[i + 3];
        float4 h0 = xv[i + 0],  h1 = xv[i + 1],  h2 = xv[i + 2],  h3 = xv[i + 3];
        a0 += w0.x * h0.x + w0.y * h0.y + w0.z * h0.z + w0.w * h0.w;
        a1 += w1.x * h1.x + w1.y * h1.y + w1.z * h1.z + w1.w * h1.w;
        a2 += w2.x * h2.x + w2.y * h2.y + w2.z * h2.z + w2.w * h2.w;
        a3 += w3.x * h3.x + w3.y * h3.y + w3.z * h3.z + w3.w * h3.w;
    }
    const float scale = ((g >> 7) == 2) ? TWOLOG2E : LOG2E;
    const float val = ((a0 + a1) + (a2 + a3) + b_ih[g] + b_hh[g]) * scale;
    xg[t * GG + (g & 127) * 4 + (g >> 7)] = val;   // packed [t][j][gate]
}

// ---------------------------------------------------------------------------
// Kernel 2: MFMA LSTM scan (batch 255). 1 block, 256 threads = 4 waves
// (R5 showed 8 waves / 2-per-SIMD regresses +85 cyc/step: MFMA issue is
// per-SIMD, not per-wave, and the 2-wave contention+skew costs more).
// r3-verified tile map: wave w owns 8 n-tiles (4 gates x 2 halves) of hidden
// slice [32w,32w+32); lane updates jsel = wbase + 16*sel + col.
//
// R6 = R4 (the 205 us best) + ONE change: the xg prefetch reloads IN PLACE
// right after its last use, instead of {temp xpf at step top, copy at step
// end}. Theory: FETCH_SIZE=579KB shows most of xg is fetched from HBM/L3
// during the scan (xgpack spread it over 8 XCDs' L2s; this CU's reads are
// mostly remote -> L2 miss, 500-900 cyc). The old copy at step end waited
// vmcnt on a load issued at the SAME step's top (~850 cyc window) --
// marginal vs miss latency, stalling ~50-300 cyc/step. In-place reload
// moves the wait to step t+2's epilogue (~1600 cyc window). R2's in-place
// attempt regressed because the per-step GLOBAL hs store sat older in the
// in-order vmcnt queue (proven by R4's fix); the store is gone now --
// each step issues exactly one vmem op.
//
// Kept from R4: exp2-prescaled weights, sign-folded fma tails, Z-seeded
// accumulators (laundered), LDS hs ring + final dump, RAW
// lgkmcnt(0)+s_barrier, one-time B-fragment launder, waves_per_eu(1,1).
// ---------------------------------------------------------------------------
__global__
__attribute__((amdgpu_flat_work_group_size(256, 256), amdgpu_waves_per_eu(1, 1)))
void scan_kernel(
    const _Float16* __restrict__ Wp,
    const float* __restrict__ xgp,
    float* __restrict__ hs)
{
    const int tid  = threadIdx.x;
    const int lane = tid & 63;
    const int w    = tid >> 6;        // wave id 0..3
    const int col  = lane & 15;
    const int quad = lane >> 4;
    const int wbase = w * 32;
    const bool sel  = (lane >= 32);
    const int jsel  = wbase + (sel ? 16 : 0) + col; // hidden index this lane updates
    const int aoff  = quad * 8;
    const bool wr   = (quad == 0) || (quad == 3);   // one writer per hidden index

    __shared__ __align__(16) _Float16 h_lds[2][HH];          // 512 B
    __shared__ __align__(16) float hs_l[BB * HH];            // 128 KB ring

    // ---- B-fragments: contiguous 16-B loads from the packed buffer ----
#define BLOADP(nt, kt) \
    half8 B##nt##_##kt = *(const half8*)(Wp + (((w * 32 + (nt) * 4 + (kt)) * 64 + lane) * 8));
#define FOR_KT(X, nt) X(nt, 0) X(nt, 1) X(nt, 2) X(nt, 3)
#define FOR_NT(X) FOR_KT(X, 0) FOR_KT(X, 1) FOR_KT(X, 2) FOR_KT(X, 3) \
                  FOR_KT(X, 4) FOR_KT(X, 5) FOR_KT(X, 6) FOR_KT(X, 7)
    FOR_NT(BLOADP)

    // ---- ONE-TIME launder: opaque-define the fragments (cannot be sunk) ----
    asm volatile("" : "+v"(B0_0), "+v"(B0_1), "+v"(B0_2), "+v"(B0_3),
                      "+v"(B1_0), "+v"(B1_1), "+v"(B1_2), "+v"(B1_3),
                      "+v"(B2_0), "+v"(B2_1), "+v"(B2_2), "+v"(B2_3),
                      "+v"(B3_0), "+v"(B3_1), "+v"(B3_2), "+v"(B3_3));
    asm volatile("" : "+v"(B4_0), "+v"(B4_1), "+v"(B4_2), "+v"(B4_3),
                      "+v"(B5_0), "+v"(B5_1), "+v"(B5_2), "+v"(B5_3),
                      "+v"(B6_0), "+v"(B6_1), "+v"(B6_2), "+v"(B6_3),
                      "+v"(B7_0), "+v"(B7_1), "+v"(B7_2), "+v"(B7_3));

    if (tid < HH) h_lds[0][tid] = (_Float16)0.f;

    // persistent zero accumulator seed (4 VGPRs, laundered so it is never
    // rematerialized as per-step v_movs)
    f32x4 Z = {0.f, 0.f, 0.f, 0.f};
    asm volatile("" : "+v"(Z));

    // 2-deep register prefetch of the packed gate biases (16 B/lane)
    const float* __restrict__ xgl = xgp + jsel * 4;
    f32x4 xg0 = *(const f32x4*)(xgl + 0 * GG);
    f32x4 xg1 = *(const f32x4*)(xgl + 1 * GG);

    float c = 0.f;   // in 2*log2e-scaled units
    __syncthreads();   // one-time full barrier (drains prologue loads too)

#define MM(a, b, cc) __builtin_amdgcn_mfma_f32_16x16x32_f16((a), (b), (cc), 0, 0, 0)
#define STEP(par, XCUR) do {                                                            \
    const int t = t2 + (par);                                                           \
    const _Float16* hl = h_lds[(par)];                                                  \
    half8 A0 = *(const half8*)(hl +  0 + aoff);                                         \
    half8 A1 = *(const half8*)(hl + 32 + aoff);                                         \
    half8 A2 = *(const half8*)(hl + 64 + aoff);                                         \
    half8 A3 = *(const half8*)(hl + 96 + aoff);                                         \
    f32x4 C0, C1, C2, C3, C4, C5, C6, C7;                                               \
    C4 = MM(A0, B4_0, Z);  C5 = MM(A0, B5_0, Z);  C0 = MM(A0, B0_0, Z);                 \
    C1 = MM(A0, B1_0, Z);  C2 = MM(A0, B2_0, Z);  C3 = MM(A0, B3_0, Z);                 \
    C6 = MM(A0, B6_0, Z);  C7 = MM(A0, B7_0, Z);                                        \
    C4 = MM(A1, B4_1, C4); C5 = MM(A1, B5_1, C5); C0 = MM(A1, B0_1, C0);                \
    C1 = MM(A1, B1_1, C1); C2 = MM(A1, B2_1, C2); C3 = MM(A1, B3_1, C3);                \
    C6 = MM(A1, B6_1, C6); C7 = MM(A1, B7_1, C7);                                       \
    C4 = MM(A2, B4_2, C4); C5 = MM(A2, B5_2, C5); C0 = MM(A2, B0_2, C0);                \
    C1 = MM(A2, B1_2, C1); C2 = MM(A2, B2_2, C2); C3 = MM(A2, B3_2, C3);                \
    C6 = MM(A2, B6_2, C6); C7 = MM(A2, B7_2, C7);                                       \
    C4 = MM(A3, B4_3, C4); C5 = MM(A3, B5_3, C5); C0 = MM(A3, B0_3, C0);                \
    C1 = MM(A3, B1_3, C1); C2 = MM(A3, B2_3, C2); C3 = MM(A3, B3_3, C3);                \
    C6 = MM(A3, B6_3, C6); C7 = MM(A3, B7_3, C7);                                       \
    /* pre-activations (exp2-prescaled): pg by 2log2e, others by log2e */               \
    float pi = (sel ? C1[0] : C0[0]) + (XCUR).x;                                        \
    float pf = (sel ? C3[0] : C2[0]) + (XCUR).y;                                        \
    float pg = (sel ? C5[0] : C4[0]) + (XCUR).z;                                        \
    float po = (sel ? C7[0] : C6[0]) + (XCUR).w;                                        \
    /* in-place reload AFTER last use: the vmcnt wait for this load lands   */          \
    /* at step t+2's epilogue (~1600 cyc window, covers HBM-miss latency)   */          \
    (XCUR) = *(const f32x4*)(xgl + ((t + 2) & (TT - 1)) * GG);                          \
    float iv = __builtin_amdgcn_rcpf(1.0f + __builtin_amdgcn_exp2f(-pi));               \
    float fv = __builtin_amdgcn_rcpf(1.0f + __builtin_amdgcn_exp2f(-pf));               \
    float ov = __builtin_amdgcn_rcpf(1.0f + __builtin_amdgcn_exp2f(-po));               \
    float Eg = __builtin_amdgcn_exp2f(fabsf(pg));                                       \
    float rg = __builtin_amdgcn_rcpf(Eg + 1.0f);                                        \
    float T  = copysignf(TWOLOG2E, pg);                                                 \
    float gvs = fmaf(-2.0f * T, rg, T);  /* = 2log2e * tanh(raw_g) */                   \
    c = fmaf(fv, c, iv * gvs);           /* c stays in 2log2e-scaled units */           \
    float Ec = __builtin_amdgcn_exp2f(fabsf(c));                                        \
    float rc = __builtin_amdgcn_rcpf(Ec + 1.0f);                                        \
    float Ao = copysignf(ov, c);                                                        \
    float hval = fmaf(-2.0f * Ao, rc, Ao);                                              \
    if (wr) {                                                                           \
        h_lds[1 - (par)][jsel] = (_Float16)hval;                                        \
        hs_l[(t & (BB - 1)) * HH + jsel] = hval; /* LDS ring, same lgkm wait */         \
    }                                                                                   \
    asm volatile("s_waitcnt lgkmcnt(0)\n\ts_barrier" ::: "memory");                     \
} while (0)

    for (int t2 = 0; t2 < TT; t2 += 2) {
        STEP(0, xg0);   // reads h_lds[0], writes h_lds[1]
        STEP(1, xg1);   // reads h_lds[1], writes h_lds[0]
    }
#undef STEP
#undef MM

    // dump hs ring (128 KB LDS -> global, coalesced); last STEP's
    // lgkmcnt(0)+barrier already made all hs_l writes visible
    const f32x4* s = (const f32x4*)hs_l;
    f32x4* d = (f32x4*)hs;
#pragma unroll 4
    for (int i = tid; i < BB * HH / 4; i += 256) d[i] = s[i];
}

// ---------------------------------------------------------------------------
// Kernel 3: out[r,:] = W2 @ (W1 @ hs[r] + b1) + b2  (no activation in ref)
// ---------------------------------------------------------------------------
__global__ __launch_bounds__(128) void mlp_kernel(
    const float* __restrict__ hs,
    const float* __restrict__ W1,
    const float* __restrict__ b1,
    const float* __restrict__ W2,
    const float* __restrict__ b2,
    float* __restrict__ out)
{
    const int r = blockIdx.x;
    const int j = threadIdx.x;

    __shared__ __align__(16) float hsh[HH];
    __shared__ __align__(16) float z[HH];

    hsh[j] = hs[r * HH + j];
    __syncthreads();

    {
        const float4* __restrict__ wrow = (const float4*)(W1 + j * HH);
        const float4* __restrict__ hv   = (const float4*)hsh;
        float acc = b1[j];
#pragma unroll
        for (int i = 0; i < 32; i++) {
            float4 ww = wrow[i], h = hv[i];
            acc += ww.x * h.x + ww.y * h.y + ww.z * h.z + ww.w * h.w;
        }
        z[j] = acc;
    }
    __syncthreads();

    if (j < OO) {
        const float4* __restrict__ wrow = (const float4*)(W2 + j * HH);
        const float4* __restrict__ zv   = (const float4*)z;
        float acc = b2[j];
#pragma unroll
        for (int i = 0; i < 32; i++) {
            float4 ww = wrow[i], zz = zv[i];
            acc += ww.x * zz.x + ww.y * zz.y + ww.z * zz.z + ww.w * zz.w;
        }
        out[r * OO + j] = acc;
    }
}

// ---------------------------------------------------------------------------
// Launch. Inputs: 0:x 1:W_ih 2:W_hh 3:b_ih 4:b_hh 5:W1 6:b1 7:W2 8:b2
// ws: xg packed (1 MB) | hs (128 KB) | Wp packed f16 frags (128 KB)
// ---------------------------------------------------------------------------
extern "C" void kernel_launch(void* const* d_in, const int* in_sizes, int n_in,
                              void* d_out, int out_size, void* d_ws, size_t ws_size,
                              hipStream_t stream) {
    const float* x    = (const float*)d_in[0];
    const float* W_ih = (const float*)d_in[1];
    const float* W_hh = (const float*)d_in[2];
    const float* b_ih = (const float*)d_in[3];
    const float* b_hh = (const float*)d_in[4];
    const float* W1   = (const float*)d_in[5];
    const float* b1   = (const float*)d_in[6];
    const float* W2   = (const float*)d_in[7];
    const float* b2   = (const float*)d_in[8];
    float* out = (float*)d_out;

    float*    xg = (float*)d_ws;                 // T*4H   = 262144 f32 (packed)
    float*    hs = xg + TT * GG;                 // 256*H  =  32768 f32
    _Float16* Wp = (_Float16*)(hs + BB * HH);    // 4H*H   =  65536 f16 (packed frags)

    xgpack_kernel<<<TT + 16, 512, 0, stream>>>(x, W_ih, b_ih, b_hh, W_hh, xg, Wp);
    scan_kernel<<<1, 256, 0, stream>>>(Wp, xg, hs);
    mlp_kernel<<<BB, 128, 0, stream>>>(hs, W1, b1, W2, b2, out);
}

// Round 7
// 325.987 us; speedup vs baseline: 1.0712x; 1.0156x over previous
//
#include <hip/hip_runtime.h>
#include <math.h>

// Problem constants (fixed by the reference)
#define BB 256
#define TT 512
#define DD 128
#define HH 128
#define GG 512   // 4*H
#define OO 64

#define LOG2E    1.44269504088896340736f
#define TWOLOG2E 2.88539008177792681472f

typedef _Float16 half8 __attribute__((ext_vector_type(8)));
typedef float    f32x4 __attribute__((ext_vector_type(4)));

// ---------------------------------------------------------------------------
// Kernel 1 (fused): blocks [0,TT): xg; blocks [TT,TT+16): weight packing.
//
// PRESCALE: W_hh rows and xg are multiplied by log2e (gates i,f,o) or
// 2*log2e (gate g) at pack time, so every activation in the scan is a bare
// v_exp_f32 (=2^x) with sign/abs folded into input modifiers. c is kept in
// 2*log2e-scaled units (scale-invariant recurrence, see scan kernel).
//
// xg[t][j][gate]: input-gate contribution, PACKED per-hidden-index so a scan
// lane reads i,f,g,o as one 16-B vector. Only batch 255 matters:
// y.reshape(T,B,O)[-1] -> flat rows (b=255, t>=256); b=255's scan needs all t.
//
// wpack (4-wave layout, r3/r8-verified fragment math; k-tile SLOT remap
// happens at load time in the scan, layout here is plain kt):
//   wave w(0..3), n-tile nt(0..7), k-tile kt(0..3), lane l:
//   row = (nt>>1)*128 + (nt&1)*16 + w*32 + (l&15); off = kt*32 + (l>>4)*8
//   dst = Wp[((w*32 + nt*4 + kt)*64 + l)*8 .. +8]
// ---------------------------------------------------------------------------
__global__ __launch_bounds__(512) void xgpack_kernel(
    const float* __restrict__ x,
    const float* __restrict__ W_ih,
    const float* __restrict__ b_ih,
    const float* __restrict__ b_hh,
    const float* __restrict__ W_hh,
    float* __restrict__ xg,
    _Float16* __restrict__ Wp)
{
    if (blockIdx.x >= TT) {   // ---- weight-packing blocks ----
        const int g = (blockIdx.x - TT) * 512 + threadIdx.x;  // 0..8191
        const int fid = g >> 6, l = g & 63;
        const int w = fid >> 5, rem = fid & 31, nt = rem >> 2, kt = rem & 3;
        const int quad = l >> 4, col = l & 15;
        const int row = (nt >> 1) * 128 + (nt & 1) * 16 + w * 32 + col;
        const int off = kt * 32 + quad * 8;
        const float ws = ((row >> 7) == 2) ? TWOLOG2E : LOG2E;  // g-gate rows 2x
        const float* s = W_hh + row * HH + off;
        _Float16* d = Wp + (size_t)g * 8;
#pragma unroll
        for (int i = 0; i < 8; i++) d[i] = (_Float16)(s[i] * ws);
        return;
    }

    const int t = blockIdx.x;
    const int g = threadIdx.x;

    __shared__ __align__(16) float xs[DD];
    if (g < DD) xs[g] = x[(255 * TT + t) * DD + g];
    __syncthreads();

    const float4* __restrict__ wrow = (const float4*)(W_ih + g * DD);
    const float4* __restrict__ xv   = (const float4*)xs;

    float a0 = 0.f, a1 = 0.f, a2 = 0.f, a3 = 0.f;
#pragma unroll
    for (int i = 0; i < DD / 4; i += 4) {
        float4 w0 = wrow[i + 0], w1 = wrow[i + 1], w2 = wrow[i + 2], w3 = wrow[i + 3];
        float4 h0 = xv[i + 0],  h1 = xv[i + 1],  h2 = xv[i + 2],  h3 = xv[i + 3];
        a0 += w0.x * h0.x + w0.y * h0.y + w0.z * h0.z + w0.w * h0.w;
        a1 += w1.x * h1.x + w1.y * h1.y + w1.z * h1.z + w1.w * h1.w;
        a2 += w2.x * h2.x + w2.y * h2.y + w2.z * h2.z + w2.w * h2.w;
        a3 += w3.x * h3.x + w3.y * h3.y + w3.z * h3.z + w3.w * h3.w;
    }
    const float scale = ((g >> 7) == 2) ? TWOLOG2E : LOG2E;
    const float val = ((a0 + a1) + (a2 + a3) + b_ih[g] + b_hh[g]) * scale;
    xg[t * GG + (g & 127) * 4 + (g >> 7)] = val;   // packed [t][j][gate]
}

// ---------------------------------------------------------------------------
// Kernel 2: MFMA LSTM scan (batch 255). 1 block, 256 threads = 4 waves.
// r3-verified tile map: wave w owns 8 n-tiles (4 gates x 2 halves) of hidden
// slice [32w,32w+32); lane updates jsel = wbase + 16*sel + col.
//
// R7: remove the post-barrier ds_read latency (~120 cyc) from the chain.
//  * k-tile SLOT PERMUTATION: slot s consumes k-tile (w+s)&3, so slot 0 is
//    the wave's OWN hidden slice [32w,32w+32) -- the region the wave itself
//    wrote this step. The next step's A0 is therefore read PRE-BARRIER
//    (after lgkmcnt(0) guarantees the own h_lds write landed; race-free:
//    own-region read-after-own-write). At barrier-exit the wave issues 8
//    MFMAs on the carried A0 immediately while A1..A3 reads complete.
//    B-fragment loads take the same runtime remap (compile-time register
//    names, runtime addresses -- no scratch). Per-wave accumulation order
//    permutes (fp shift ~1e-7, far under the f16-h error floor).
//  * DEFERRED hs_l ring write: h_{t-1} written at step t's top (post-
//    barrier, off the chain) instead of before lgkmcnt(0); the barrier wait
//    now covers only the 2-B h_lds write. h_511 written post-loop +
//    __syncthreads() before the dump.
// Kept (each verified): 4 waves/1-per-SIMD (R5: 8w regresses), exp2-
// prescaled weights + sign-folded tails (R2-R6), Z-seeded accumulators,
// in-place xg reload (R6: position-neutral), LDS hs ring (R4: vmcnt
// entanglement), RAW lgkmcnt(0)+s_barrier (R1), B-fragment launder.
// ---------------------------------------------------------------------------
__global__
__attribute__((amdgpu_flat_work_group_size(256, 256), amdgpu_waves_per_eu(1, 1)))
void scan_kernel(
    const _Float16* __restrict__ Wp,
    const float* __restrict__ xgp,
    float* __restrict__ hs)
{
    const int tid  = threadIdx.x;
    const int lane = tid & 63;
    const int w    = tid >> 6;        // wave id 0..3
    const int col  = lane & 15;
    const int quad = lane >> 4;
    const int wbase = w * 32;
    const bool sel  = (lane >= 32);
    const int jsel  = wbase + (sel ? 16 : 0) + col; // hidden index this lane updates
    const int aoff  = quad * 8;
    const bool wr   = (quad == 0) || (quad == 3);   // one writer per hidden index

    // element offsets of A-fragment slots 0..3 (slot s = k-tile (w+s)&3)
    const int offA0 = ((w + 0) & 3) * 32 + aoff;   // own slice
    const int offA1 = ((w + 1) & 3) * 32 + aoff;
    const int offA2 = ((w + 2) & 3) * 32 + aoff;
    const int offA3 = ((w + 3) & 3) * 32 + aoff;

    __shared__ __align__(16) _Float16 h_lds[2][HH];          // 512 B
    __shared__ __align__(16) float hs_l[BB * HH];            // 128 KB ring

    // ---- B-fragments: slot s holds W k-tile (w+s)&3 (runtime remap) ----
#define BLOADP(nt, s) \
    half8 B##nt##_##s = *(const half8*)(Wp + (((w * 32 + (nt) * 4 + ((w + (s)) & 3)) * 64 + lane) * 8));
#define FOR_KT(X, nt) X(nt, 0) X(nt, 1) X(nt, 2) X(nt, 3)
#define FOR_NT(X) FOR_KT(X, 0) FOR_KT(X, 1) FOR_KT(X, 2) FOR_KT(X, 3) \
                  FOR_KT(X, 4) FOR_KT(X, 5) FOR_KT(X, 6) FOR_KT(X, 7)
    FOR_NT(BLOADP)

    // ---- ONE-TIME launder: opaque-define the fragments (cannot be sunk) ----
    asm volatile("" : "+v"(B0_0), "+v"(B0_1), "+v"(B0_2), "+v"(B0_3),
                      "+v"(B1_0), "+v"(B1_1), "+v"(B1_2), "+v"(B1_3),
                      "+v"(B2_0), "+v"(B2_1), "+v"(B2_2), "+v"(B2_3),
                      "+v"(B3_0), "+v"(B3_1), "+v"(B3_2), "+v"(B3_3));
    asm volatile("" : "+v"(B4_0), "+v"(B4_1), "+v"(B4_2), "+v"(B4_3),
                      "+v"(B5_0), "+v"(B5_1), "+v"(B5_2), "+v"(B5_3),
                      "+v"(B6_0), "+v"(B6_1), "+v"(B6_2), "+v"(B6_3),
                      "+v"(B7_0), "+v"(B7_1), "+v"(B7_2), "+v"(B7_3));

    if (tid < HH) h_lds[0][tid] = (_Float16)0.f;

    // persistent zero accumulator seed (4 VGPRs, laundered so it is never
    // rematerialized as per-step v_movs)
    f32x4 Z = {0.f, 0.f, 0.f, 0.f};
    asm volatile("" : "+v"(Z));

    // 2-deep register prefetch of the packed gate biases (16 B/lane)
    const float* __restrict__ xgl = xgp + jsel * 4;
    f32x4 xg0 = *(const f32x4*)(xgl + 0 * GG);
    f32x4 xg1 = *(const f32x4*)(xgl + 1 * GG);

    float c = 0.f;          // in 2*log2e-scaled units
    float hval_prev = 0.f;  // deferred hs_l ring write (one step behind)
    __syncthreads();        // h_lds[0] init visible; drains prologue loads

    // carried A0 (own slice of h_lds[0]) for step 0
    half8 A0c = *(const half8*)(&h_lds[0][0] + offA0);

#define MM(a, b, cc) __builtin_amdgcn_mfma_f32_16x16x32_f16((a), (b), (cc), 0, 0, 0)
#define STEP(par, XCUR) do {                                                            \
    const int t = t2 + (par);                                                           \
    const _Float16* hl = h_lds[(par)];                                                  \
    half8 A0 = A0c;                                                                     \
    half8 A1 = *(const half8*)(hl + offA1);                                             \
    half8 A2 = *(const half8*)(hl + offA2);                                             \
    half8 A3 = *(const half8*)(hl + offA3);                                             \
    /* deferred ring write of h_{t-1} (post-barrier => off the chain) */                \
    if (wr) hs_l[((t - 1) & (BB - 1)) * HH + jsel] = hval_prev;                         \
    f32x4 C0, C1, C2, C3, C4, C5, C6, C7;                                               \
    C4 = MM(A0, B4_0, Z);  C5 = MM(A0, B5_0, Z);  C0 = MM(A0, B0_0, Z);                 \
    C1 = MM(A0, B1_0, Z);  C2 = MM(A0, B2_0, Z);  C3 = MM(A0, B3_0, Z);                 \
    C6 = MM(A0, B6_0, Z);  C7 = MM(A0, B7_0, Z);                                        \
    C4 = MM(A1, B4_1, C4); C5 = MM(A1, B5_1, C5); C0 = MM(A1, B0_1, C0);                \
    C1 = MM(A1, B1_1, C1); C2 = MM(A1, B2_1, C2); C3 = MM(A1, B3_1, C3);                \
    C6 = MM(A1, B6_1, C6); C7 = MM(A1, B7_1, C7);                                       \
    C4 = MM(A2, B4_2, C4); C5 = MM(A2, B5_2, C5); C0 = MM(A2, B0_2, C0);                \
    C1 = MM(A2, B1_2, C1); C2 = MM(A2, B2_2, C2); C3 = MM(A2, B3_2, C3);                \
    C6 = MM(A2, B6_2, C6); C7 = MM(A2, B7_2, C7);                                       \
    C4 = MM(A3, B4_3, C4); C5 = MM(A3, B5_3, C5); C0 = MM(A3, B0_3, C0);                \
    C1 = MM(A3, B1_3, C1); C2 = MM(A3, B2_3, C2); C3 = MM(A3, B3_3, C3);                \
    C6 = MM(A3, B6_3, C6); C7 = MM(A3, B7_3, C7);                                       \
    /* pre-activations (exp2-prescaled): pg by 2log2e, others by log2e */               \
    float pi = (sel ? C1[0] : C0[0]) + (XCUR).x;                                        \
    float pf = (sel ? C3[0] : C2[0]) + (XCUR).y;                                        \
    float pg = (sel ? C5[0] : C4[0]) + (XCUR).z;                                        \
    float po = (sel ? C7[0] : C6[0]) + (XCUR).w;                                        \
    /* in-place reload AFTER last use (R6: fully hidden at 2-step depth) */             \
    (XCUR) = *(const f32x4*)(xgl + ((t + 2) & (TT - 1)) * GG);                          \
    float iv = __builtin_amdgcn_rcpf(1.0f + __builtin_amdgcn_exp2f(-pi));               \
    float fv = __builtin_amdgcn_rcpf(1.0f + __builtin_amdgcn_exp2f(-pf));               \
    float ov = __builtin_amdgcn_rcpf(1.0f + __builtin_amdgcn_exp2f(-po));               \
    float Eg = __builtin_amdgcn_exp2f(fabsf(pg));                                       \
    float rg = __builtin_amdgcn_rcpf(Eg + 1.0f);                                        \
    float T  = copysignf(TWOLOG2E, pg);                                                 \
    float gvs = fmaf(-2.0f * T, rg, T);  /* = 2log2e * tanh(raw_g) */                   \
    c = fmaf(fv, c, iv * gvs);           /* c stays in 2log2e-scaled units */           \
    float Ec = __builtin_amdgcn_exp2f(fabsf(c));                                        \
    float rc = __builtin_amdgcn_rcpf(Ec + 1.0f);                                        \
    float Ao = copysignf(ov, c);                                                        \
    float hval = fmaf(-2.0f * Ao, rc, Ao);                                              \
    if (wr) h_lds[1 - (par)][jsel] = (_Float16)hval;                                    \
    hval_prev = hval;                                                                   \
    asm volatile("s_waitcnt lgkmcnt(0)" ::: "memory");                                  \
    /* pre-barrier prefetch of next step's A0 = own slice, just written */              \
    A0c = *(const half8*)(&h_lds[1 - (par)][0] + offA0);                                \
    asm volatile("s_barrier" ::: "memory");                                             \
} while (0)

    for (int t2 = 0; t2 < TT; t2 += 2) {
        STEP(0, xg0);   // reads h_lds[0], writes h_lds[1]
        STEP(1, xg1);   // reads h_lds[1], writes h_lds[0]
    }
#undef STEP
#undef MM

    // final deferred ring write: h_511 -> slot 255
    if (wr) hs_l[(BB - 1) * HH + jsel] = hval_prev;
    __syncthreads();

    // dump hs ring (128 KB LDS -> global, coalesced)
    const f32x4* s = (const f32x4*)hs_l;
    f32x4* d = (f32x4*)hs;
#pragma unroll 4
    for (int i = tid; i < BB * HH / 4; i += 256) d[i] = s[i];
}

// ---------------------------------------------------------------------------
// Kernel 3: out[r,:] = W2 @ (W1 @ hs[r] + b1) + b2  (no activation in ref)
// ---------------------------------------------------------------------------
__global__ __launch_bounds__(128) void mlp_kernel(
    const float* __restrict__ hs,
    const float* __restrict__ W1,
    const float* __restrict__ b1,
    const float* __restrict__ W2,
    const float* __restrict__ b2,
    float* __restrict__ out)
{
    const int r = blockIdx.x;
    const int j = threadIdx.x;

    __shared__ __align__(16) float hsh[HH];
    __shared__ __align__(16) float z[HH];

    hsh[j] = hs[r * HH + j];
    __syncthreads();

    {
        const float4* __restrict__ wrow = (const float4*)(W1 + j * HH);
        const float4* __restrict__ hv   = (const float4*)hsh;
        float acc = b1[j];
#pragma unroll
        for (int i = 0; i < 32; i++) {
            float4 ww = wrow[i], h = hv[i];
            acc += ww.x * h.x + ww.y * h.y + ww.z * h.z + ww.w * h.w;
        }
        z[j] = acc;
    }
    __syncthreads();

    if (j < OO) {
        const float4* __restrict__ wrow = (const float4*)(W2 + j * HH);
        const float4* __restrict__ zv   = (const float4*)z;
        float acc = b2[j];
#pragma unroll
        for (int i = 0; i < 32; i++) {
            float4 ww = wrow[i], zz = zv[i];
            acc += ww.x * zz.x + ww.y * zz.y + ww.z * zz.z + ww.w * zz.w;
        }
        out[r * OO + j] = acc;
    }
}

// ---------------------------------------------------------------------------
// Launch. Inputs: 0:x 1:W_ih 2:W_hh 3:b_ih 4:b_hh 5:W1 6:b1 7:W2 8:b2
// ws: xg packed (1 MB) | hs (128 KB) | Wp packed f16 frags (128 KB)
// ---------------------------------------------------------------------------
extern "C" void kernel_launch(void* const* d_in, const int* in_sizes, int n_in,
                              void* d_out, int out_size, void* d_ws, size_t ws_size,
                              hipStream_t stream) {
    const float* x    = (const float*)d_in[0];
    const float* W_ih = (const float*)d_in[1];
    const float* W_hh = (const float*)d_in[2];
    const float* b_ih = (const float*)d_in[3];
    const float* b_hh = (const float*)d_in[4];
    const float* W1   = (const float*)d_in[5];
    const float* b1   = (const float*)d_in[6];
    const float* W2   = (const float*)d_in[7];
    const float* b2   = (const float*)d_in[8];
    float* out = (float*)d_out;

    float*    xg = (float*)d_ws;                 // T*4H   = 262144 f32 (packed)
    float*    hs = xg + TT * GG;                 // 256*H  =  32768 f32
    _Float16* Wp = (_Float16*)(hs + BB * HH);    // 4H*H   =  65536 f16 (packed frags)

    xgpack_kernel<<<TT + 16, 512, 0, stream>>>(x, W_ih, b_ih, b_hh, W_hh, xg, Wp);
    scan_kernel<<<1, 256, 0, stream>>>(Wp, xg, hs);
    mlp_kernel<<<BB, 128, 0, stream>>>(hs, W1, b1, W2, b2, out);
}

// Round 8
// 325.180 us; speedup vs baseline: 1.0738x; 1.0025x over previous
//
#include <hip/hip_runtime.h>
#include <math.h>

// Problem constants (fixed by the reference)
#define BB 256
#define TT 512
#define DD 128
#define HH 128
#define GG 512   // 4*H
#define OO 64

#define LOG2E    1.44269504088896340736f
#define TWOLOG2E 2.88539008177792681472f

typedef _Float16 half8 __attribute__((ext_vector_type(8)));
typedef float    f32x4 __attribute__((ext_vector_type(4)));

// ---------------------------------------------------------------------------
// Kernel 1 (fused): blocks [0,TT): xg; blocks [TT,TT+16): weight packing.
//
// PRESCALE: W_hh rows and xg are multiplied by log2e (gates i,f,o) or
// 2*log2e (gate g) at pack time, so every activation in the scan is a bare
// v_exp_f32 (=2^x) with sign/abs folded into input modifiers. c is kept in
// 2*log2e-scaled units (scale-invariant recurrence, see scan kernel).
//
// xg[t][j][gate]: input-gate contribution, PACKED per-hidden-index so a scan
// lane reads i,f,g,o as one 16-B vector. Only batch 255 matters:
// y.reshape(T,B,O)[-1] -> flat rows (b=255, t>=256); b=255's scan needs all t.
//
// wpack (4-wave layout, r3/r8-verified fragment math; k-tile SLOT remap
// happens at load time in the scan, layout here is plain kt):
//   wave w(0..3), n-tile nt(0..7), k-tile kt(0..3), lane l:
//   row = (nt>>1)*128 + (nt&1)*16 + w*32 + (l&15); off = kt*32 + (l>>4)*8
//   dst = Wp[((w*32 + nt*4 + kt)*64 + l)*8 .. +8]
// ---------------------------------------------------------------------------
__global__ __launch_bounds__(512) void xgpack_kernel(
    const float* __restrict__ x,
    const float* __restrict__ W_ih,
    const float* __restrict__ b_ih,
    const float* __restrict__ b_hh,
    const float* __restrict__ W_hh,
    float* __restrict__ xg,
    _Float16* __restrict__ Wp)
{
    if (blockIdx.x >= TT) {   // ---- weight-packing blocks ----
        const int g = (blockIdx.x - TT) * 512 + threadIdx.x;  // 0..8191
        const int fid = g >> 6, l = g & 63;
        const int w = fid >> 5, rem = fid & 31, nt = rem >> 2, kt = rem & 3;
        const int quad = l >> 4, col = l & 15;
        const int row = (nt >> 1) * 128 + (nt & 1) * 16 + w * 32 + col;
        const int off = kt * 32 + quad * 8;
        const float ws = ((row >> 7) == 2) ? TWOLOG2E : LOG2E;  // g-gate rows 2x
        const float* s = W_hh + row * HH + off;
        _Float16* d = Wp + (size_t)g * 8;
#pragma unroll
        for (int i = 0; i < 8; i++) d[i] = (_Float16)(s[i] * ws);
        return;
    }

    const int t = blockIdx.x;
    const int g = threadIdx.x;

    __shared__ __align__(16) float xs[DD];
    if (g < DD) xs[g] = x[(255 * TT + t) * DD + g];
    __syncthreads();

    const float4* __restrict__ wrow = (const float4*)(W_ih + g * DD);
    const float4* __restrict__ xv   = (const float4*)xs;

    float a0 = 0.f, a1 = 0.f, a2 = 0.f, a3 = 0.f;
#pragma unroll
    for (int i = 0; i < DD / 4; i += 4) {
        float4 w0 = wrow[i + 0], w1 = wrow[i + 1], w2 = wrow[i + 2], w3 = wrow[i + 3];
        float4 h0 = xv[i + 0],  h1 = xv[i + 1],  h2 = xv[i + 2],  h3 = xv[i + 3];
        a0 += w0.x * h0.x + w0.y * h0.y + w0.z * h0.z + w0.w * h0.w;
        a1 += w1.x * h1.x + w1.y * h1.y + w1.z * h1.z + w1.w * h1.w;
        a2 += w2.x * h2.x + w2.y * h2.y + w2.z * h2.z + w2.w * h2.w;
        a3 += w3.x * h3.x + w3.y * h3.y + w3.z * h3.z + w3.w * h3.w;
    }
    const float scale = ((g >> 7) == 2) ? TWOLOG2E : LOG2E;
    const float val = ((a0 + a1) + (a2 + a3) + b_ih[g] + b_hh[g]) * scale;
    xg[t * GG + (g & 127) * 4 + (g >> 7)] = val;   // packed [t][j][gate]
}

// ---------------------------------------------------------------------------
// Kernel 2: MFMA LSTM scan (batch 255). 1 block, 256 threads = 4 waves.
// r3-verified tile map: wave w owns 8 n-tiles (4 gates x 2 halves) of hidden
// slice [32w,32w+32); lane updates jsel = wbase + 16*sel + col.
//
// R8: overlap the A0c prefetch latency with the pre-barrier wait.
//  * TAIL REORDER + lgkmcnt(1): emitted order is now {h_lds write -> fence
//    -> A0c ds_read -> s_waitcnt lgkmcnt(1) -> s_barrier}. DS ops retire in
//    order, and the only outstanding lgkm ops at the wait are [h_write,
//    A0c_read] (ring write fenced early, A1-3 reads consumed by MFMAs), so
//    lgkmcnt(1) guarantees the h_write retired (the cross-wave visibility
//    requirement) while the A0c read's ~120-cyc latency overlaps the wait
//    AND the barrier instead of starting after them (R7 exposed ~25-60 cyc
//    of it at the next step's first MFMA).
//  * UNCONDITIONAL LDS writes: quad pairs (0,1)/(2,3) hold identical hval
//    for the same jsel; letting all 4 quads write the same value to the
//    same address is benign, removes the `if (wr)` mask, and makes the
//    instruction stream branch-free so the lgkm count is static.
// Kept (each verified): k-tile slot permutation + pre-barrier A0c read +
// deferred ring write (R7, -24 cyc), 4 waves/1-per-SIMD (R5: 8w regresses),
// exp2-prescaled weights + sign-folded tails (R2-R6), Z-seeded accumulators,
// in-place xg reload (R6), LDS hs ring (R4: vmcnt entanglement), B-fragment
// launder, waves_per_eu(1,1).
// ---------------------------------------------------------------------------
__global__
__attribute__((amdgpu_flat_work_group_size(256, 256), amdgpu_waves_per_eu(1, 1)))
void scan_kernel(
    const _Float16* __restrict__ Wp,
    const float* __restrict__ xgp,
    float* __restrict__ hs)
{
    const int tid  = threadIdx.x;
    const int lane = tid & 63;
    const int w    = tid >> 6;        // wave id 0..3
    const int col  = lane & 15;
    const int quad = lane >> 4;
    const int wbase = w * 32;
    const bool sel  = (lane >= 32);
    const int jsel  = wbase + (sel ? 16 : 0) + col; // hidden index this lane updates
    const int aoff  = quad * 8;

    // element offsets of A-fragment slots 0..3 (slot s = k-tile (w+s)&3)
    const int offA0 = ((w + 0) & 3) * 32 + aoff;   // own slice
    const int offA1 = ((w + 1) & 3) * 32 + aoff;
    const int offA2 = ((w + 2) & 3) * 32 + aoff;
    const int offA3 = ((w + 3) & 3) * 32 + aoff;

    __shared__ __align__(16) _Float16 h_lds[2][HH];          // 512 B
    __shared__ __align__(16) float hs_l[BB * HH];            // 128 KB ring

    // ---- B-fragments: slot s holds W k-tile (w+s)&3 (runtime remap) ----
#define BLOADP(nt, s) \
    half8 B##nt##_##s = *(const half8*)(Wp + (((w * 32 + (nt) * 4 + ((w + (s)) & 3)) * 64 + lane) * 8));
#define FOR_KT(X, nt) X(nt, 0) X(nt, 1) X(nt, 2) X(nt, 3)
#define FOR_NT(X) FOR_KT(X, 0) FOR_KT(X, 1) FOR_KT(X, 2) FOR_KT(X, 3) \
                  FOR_KT(X, 4) FOR_KT(X, 5) FOR_KT(X, 6) FOR_KT(X, 7)
    FOR_NT(BLOADP)

    // ---- ONE-TIME launder: opaque-define the fragments (cannot be sunk) ----
    asm volatile("" : "+v"(B0_0), "+v"(B0_1), "+v"(B0_2), "+v"(B0_3),
                      "+v"(B1_0), "+v"(B1_1), "+v"(B1_2), "+v"(B1_3),
                      "+v"(B2_0), "+v"(B2_1), "+v"(B2_2), "+v"(B2_3),
                      "+v"(B3_0), "+v"(B3_1), "+v"(B3_2), "+v"(B3_3));
    asm volatile("" : "+v"(B4_0), "+v"(B4_1), "+v"(B4_2), "+v"(B4_3),
                      "+v"(B5_0), "+v"(B5_1), "+v"(B5_2), "+v"(B5_3),
                      "+v"(B6_0), "+v"(B6_1), "+v"(B6_2), "+v"(B6_3),
                      "+v"(B7_0), "+v"(B7_1), "+v"(B7_2), "+v"(B7_3));

    if (tid < HH) h_lds[0][tid] = (_Float16)0.f;

    // persistent zero accumulator seed (4 VGPRs, laundered so it is never
    // rematerialized as per-step v_movs)
    f32x4 Z = {0.f, 0.f, 0.f, 0.f};
    asm volatile("" : "+v"(Z));

    // 2-deep register prefetch of the packed gate biases (16 B/lane)
    const float* __restrict__ xgl = xgp + jsel * 4;
    f32x4 xg0 = *(const f32x4*)(xgl + 0 * GG);
    f32x4 xg1 = *(const f32x4*)(xgl + 1 * GG);

    float c = 0.f;          // in 2*log2e-scaled units
    float hval_prev = 0.f;  // deferred hs_l ring write (one step behind)
    __syncthreads();        // h_lds[0] init visible; drains prologue loads

    // carried A0 (own slice of h_lds[0]) for step 0
    half8 A0c = *(const half8*)(&h_lds[0][0] + offA0);

#define MM(a, b, cc) __builtin_amdgcn_mfma_f32_16x16x32_f16((a), (b), (cc), 0, 0, 0)
#define STEP(par, XCUR) do {                                                            \
    const int t = t2 + (par);                                                           \
    const _Float16* hl = h_lds[(par)];                                                  \
    half8 A0 = A0c;                                                                     \
    half8 A1 = *(const half8*)(hl + offA1);                                             \
    half8 A2 = *(const half8*)(hl + offA2);                                             \
    half8 A3 = *(const half8*)(hl + offA3);                                             \
    /* deferred ring write of h_{t-1}: unconditional (dup lanes, same val), */          \
    /* fenced so it issues early and retires under the MFMAs               */           \
    hs_l[((t - 1) & (BB - 1)) * HH + jsel] = hval_prev;                                 \
    asm volatile("" ::: "memory");                                                      \
    f32x4 C0, C1, C2, C3, C4, C5, C6, C7;                                               \
    C4 = MM(A0, B4_0, Z);  C5 = MM(A0, B5_0, Z);  C0 = MM(A0, B0_0, Z);                 \
    C1 = MM(A0, B1_0, Z);  C2 = MM(A0, B2_0, Z);  C3 = MM(A0, B3_0, Z);                 \
    C6 = MM(A0, B6_0, Z);  C7 = MM(A0, B7_0, Z);                                        \
    C4 = MM(A1, B4_1, C4); C5 = MM(A1, B5_1, C5); C0 = MM(A1, B0_1, C0);                \
    C1 = MM(A1, B1_1, C1); C2 = MM(A1, B2_1, C2); C3 = MM(A1, B3_1, C3);                \
    C6 = MM(A1, B6_1, C6); C7 = MM(A1, B7_1, C7);                                       \
    C4 = MM(A2, B4_2, C4); C5 = MM(A2, B5_2, C5); C0 = MM(A2, B0_2, C0);                \
    C1 = MM(A2, B1_2, C1); C2 = MM(A2, B2_2, C2); C3 = MM(A2, B3_2, C3);                \
    C6 = MM(A2, B6_2, C6); C7 = MM(A2, B7_2, C7);                                       \
    C4 = MM(A3, B4_3, C4); C5 = MM(A3, B5_3, C5); C0 = MM(A3, B0_3, C0);                \
    C1 = MM(A3, B1_3, C1); C2 = MM(A3, B2_3, C2); C3 = MM(A3, B3_3, C3);                \
    C6 = MM(A3, B6_3, C6); C7 = MM(A3, B7_3, C7);                                       \
    /* pre-activations (exp2-prescaled): pg by 2log2e, others by log2e */               \
    float pi = (sel ? C1[0] : C0[0]) + (XCUR).x;                                        \
    float pf = (sel ? C3[0] : C2[0]) + (XCUR).y;                                        \
    float pg = (sel ? C5[0] : C4[0]) + (XCUR).z;                                        \
    float po = (sel ? C7[0] : C6[0]) + (XCUR).w;                                        \
    /* in-place reload AFTER last use (R6: fully hidden at 2-step depth) */             \
    (XCUR) = *(const f32x4*)(xgl + ((t + 2) & (TT - 1)) * GG);                          \
    float iv = __builtin_amdgcn_rcpf(1.0f + __builtin_amdgcn_exp2f(-pi));               \
    float fv = __builtin_amdgcn_rcpf(1.0f + __builtin_amdgcn_exp2f(-pf));               \
    float ov = __builtin_amdgcn_rcpf(1.0f + __builtin_amdgcn_exp2f(-po));               \
    float Eg = __builtin_amdgcn_exp2f(fabsf(pg));                                       \
    float rg = __builtin_amdgcn_rcpf(Eg + 1.0f);                                        \
    float T  = copysignf(TWOLOG2E, pg);                                                 \
    float gvs = fmaf(-2.0f * T, rg, T);  /* = 2log2e * tanh(raw_g) */                   \
    c = fmaf(fv, c, iv * gvs);           /* c stays in 2log2e-scaled units */           \
    float Ec = __builtin_amdgcn_exp2f(fabsf(c));                                        \
    float rc = __builtin_amdgcn_rcpf(Ec + 1.0f);                                        \
    float Ao = copysignf(ov, c);                                                        \
    float hval = fmaf(-2.0f * Ao, rc, Ao);                                              \
    h_lds[1 - (par)][jsel] = (_Float16)hval;   /* unconditional (dup-safe) */           \
    hval_prev = hval;                                                                   \
    asm volatile("" ::: "memory");             /* order: h write < A0c read */          \
    /* pre-barrier prefetch of next step's A0 = own slice, just written.    */          \
    /* lgkmcnt(1): DS retires in order -> h_write done, A0c read stays in   */          \
    /* flight across the barrier (latency overlaps wait+barrier).           */          \
    A0c = *(const half8*)(&h_lds[1 - (par)][0] + offA0);                                \
    asm volatile("s_waitcnt lgkmcnt(1)\n\ts_barrier" ::: "memory");                     \
} while (0)

    for (int t2 = 0; t2 < TT; t2 += 2) {
        STEP(0, xg0);   // reads h_lds[0], writes h_lds[1]
        STEP(1, xg1);   // reads h_lds[1], writes h_lds[0]
    }
#undef STEP
#undef MM

    // final deferred ring write: h_511 -> slot 255
    hs_l[(BB - 1) * HH + jsel] = hval_prev;
    __syncthreads();

    // dump hs ring (128 KB LDS -> global, coalesced)
    const f32x4* s = (const f32x4*)hs_l;
    f32x4* d = (f32x4*)hs;
#pragma unroll 4
    for (int i = tid; i < BB * HH / 4; i += 256) d[i] = s[i];
}

// ---------------------------------------------------------------------------
// Kernel 3: out[r,:] = W2 @ (W1 @ hs[r] + b1) + b2  (no activation in ref)
// ---------------------------------------------------------------------------
__global__ __launch_bounds__(128) void mlp_kernel(
    const float* __restrict__ hs,
    const float* __restrict__ W1,
    const float* __restrict__ b1,
    const float* __restrict__ W2,
    const float* __restrict__ b2,
    float* __restrict__ out)
{
    const int r = blockIdx.x;
    const int j = threadIdx.x;

    __shared__ __align__(16) float hsh[HH];
    __shared__ __align__(16) float z[HH];

    hsh[j] = hs[r * HH + j];
    __syncthreads();

    {
        const float4* __restrict__ wrow = (const float4*)(W1 + j * HH);
        const float4* __restrict__ hv   = (const float4*)hsh;
        float acc = b1[j];
#pragma unroll
        for (int i = 0; i < 32; i++) {
            float4 ww = wrow[i], h = hv[i];
            acc += ww.x * h.x + ww.y * h.y + ww.z * h.z + ww.w * h.w;
        }
        z[j] = acc;
    }
    __syncthreads();

    if (j < OO) {
        const float4* __restrict__ wrow = (const float4*)(W2 + j * HH);
        const float4* __restrict__ zv   = (const float4*)z;
        float acc = b2[j];
#pragma unroll
        for (int i = 0; i < 32; i++) {
            float4 ww = wrow[i], zz = zv[i];
            acc += ww.x * zz.x + ww.y * zz.y + ww.z * zz.z + ww.w * zz.w;
        }
        out[r * OO + j] = acc;
    }
}

// ---------------------------------------------------------------------------
// Launch. Inputs: 0:x 1:W_ih 2:W_hh 3:b_ih 4:b_hh 5:W1 6:b1 7:W2 8:b2
// ws: xg packed (1 MB) | hs (128 KB) | Wp packed f16 frags (128 KB)
// ---------------------------------------------------------------------------
extern "C" void kernel_launch(void* const* d_in, const int* in_sizes, int n_in,
                              void* d_out, int out_size, void* d_ws, size_t ws_size,
                              hipStream_t stream) {
    const float* x    = (const float*)d_in[0];
    const float* W_ih = (const float*)d_in[1];
    const float* W_hh = (const float*)d_in[2];
    const float* b_ih = (const float*)d_in[3];
    const float* b_hh = (const float*)d_in[4];
    const float* W1   = (const float*)d_in[5];
    const float* b1   = (const float*)d_in[6];
    const float* W2   = (const float*)d_in[7];
    const float* b2   = (const float*)d_in[8];
    float* out = (float*)d_out;

    float*    xg = (float*)d_ws;                 // T*4H   = 262144 f32 (packed)
    float*    hs = xg + TT * GG;                 // 256*H  =  32768 f32
    _Float16* Wp = (_Float16*)(hs + BB * HH);    // 4H*H   =  65536 f16 (packed frags)

    xgpack_kernel<<<TT + 16, 512, 0, stream>>>(x, W_ih, b_ih, b_hh, W_hh, xg, Wp);
    scan_kernel<<<1, 256, 0, stream>>>(Wp, xg, hs);
    mlp_kernel<<<BB, 128, 0, stream>>>(hs, W1, b1, W2, b2, out);
}

// Round 9
// 323.054 us; speedup vs baseline: 1.0809x; 1.0066x over previous
//
#include <hip/hip_runtime.h>
#include <math.h>

// Problem constants (fixed by the reference)
#define BB 256
#define TT 512
#define DD 128
#define HH 128
#define GG 512   // 4*H
#define OO 64
#define TI 8     // timesteps per xgpack block (W_ih register-blocking factor)
#define RI 8     // rows per mlp block (W1/W2 register-blocking factor)

#define LOG2E    1.44269504088896340736f
#define TWOLOG2E 2.88539008177792681472f

typedef _Float16 half8 __attribute__((ext_vector_type(8)));
typedef float    f32x4 __attribute__((ext_vector_type(4)));

// ---------------------------------------------------------------------------
// Kernel 1 (fused): blocks [0,TT/TI): xg (8 timesteps each); blocks
// [TT/TI, TT/TI+16): weight packing.
//
// R9: register-blocking over timesteps. The old kernel used one block per
// timestep -> every block re-read the full 256 KB W_ih (128 MB of L2/L3
// traffic across 512 blocks). Now each thread loads its W_ih row chunk ONCE
// and applies it to 8 x-rows staged in LDS (broadcast reads, conflict-free).
// W_ih traffic /8; grid 528 -> 80 blocks.
//
// PRESCALE: W_hh rows and xg are multiplied by log2e (gates i,f,o) or
// 2*log2e (gate g) at pack time, so every activation in the scan is a bare
// v_exp_f32 (=2^x) with sign/abs folded into input modifiers. c is kept in
// 2*log2e-scaled units (scale-invariant recurrence, see scan kernel).
//
// xg[t][j][gate]: input-gate contribution, PACKED per-hidden-index so a scan
// lane reads i,f,g,o as one 16-B vector. Only batch 255 matters:
// y.reshape(T,B,O)[-1] -> flat rows (b=255, t>=256); b=255's scan needs all t.
//
// wpack (4-wave layout, r3/r8-verified fragment math; k-tile SLOT remap
// happens at load time in the scan, layout here is plain kt):
//   wave w(0..3), n-tile nt(0..7), k-tile kt(0..3), lane l:
//   row = (nt>>1)*128 + (nt&1)*16 + w*32 + (l&15); off = kt*32 + (l>>4)*8
//   dst = Wp[((w*32 + nt*4 + kt)*64 + l)*8 .. +8]
// ---------------------------------------------------------------------------
__global__ __launch_bounds__(512) void xgpack_kernel(
    const float* __restrict__ x,
    const float* __restrict__ W_ih,
    const float* __restrict__ b_ih,
    const float* __restrict__ b_hh,
    const float* __restrict__ W_hh,
    float* __restrict__ xg,
    _Float16* __restrict__ Wp)
{
    if (blockIdx.x >= TT / TI) {   // ---- weight-packing blocks ----
        const int g = (blockIdx.x - TT / TI) * 512 + threadIdx.x;  // 0..8191
        const int fid = g >> 6, l = g & 63;
        const int w = fid >> 5, rem = fid & 31, nt = rem >> 2, kt = rem & 3;
        const int quad = l >> 4, col = l & 15;
        const int row = (nt >> 1) * 128 + (nt & 1) * 16 + w * 32 + col;
        const int off = kt * 32 + quad * 8;
        const float ws = ((row >> 7) == 2) ? TWOLOG2E : LOG2E;  // g-gate rows 2x
        const float* s = W_hh + row * HH + off;
        _Float16* d = Wp + (size_t)g * 8;
#pragma unroll
        for (int i = 0; i < 8; i++) d[i] = (_Float16)(s[i] * ws);
        return;
    }

    const int t0 = blockIdx.x * TI;
    const int g  = threadIdx.x;

    __shared__ __align__(16) float xs[TI][DD];   // 4 KB: 8 x-rows
    {
        const float4* src = (const float4*)(x + (size_t)(255 * TT + t0) * DD);
        float4* dst = (float4*)&xs[0][0];
        for (int i = threadIdx.x; i < TI * DD / 4; i += 512) dst[i] = src[i];
    }
    __syncthreads();

    const float4* __restrict__ wrow = (const float4*)(W_ih + g * DD);
    const float bias = b_ih[g] + b_hh[g];
    const float scale = ((g >> 7) == 2) ? TWOLOG2E : LOG2E;

    float acc[TI];
#pragma unroll
    for (int r = 0; r < TI; r++) acc[r] = 0.f;

#pragma unroll 8
    for (int i = 0; i < DD / 4; i++) {
        const float4 ww = wrow[i];        // W chunk loaded ONCE, used 8x
#pragma unroll
        for (int r = 0; r < TI; r++) {
            const float4 h = ((const float4*)&xs[r][0])[i];   // LDS broadcast
            acc[r] += ww.x * h.x + ww.y * h.y + ww.z * h.z + ww.w * h.w;
        }
    }
#pragma unroll
    for (int r = 0; r < TI; r++) {
        const float val = (acc[r] + bias) * scale;
        xg[(t0 + r) * GG + (g & 127) * 4 + (g >> 7)] = val;   // packed [t][j][gate]
    }
}

// ---------------------------------------------------------------------------
// Kernel 2: MFMA LSTM scan (batch 255). 1 block, 256 threads = 4 waves.
// UNCHANGED from R8 (199.7 us best). r3-verified tile map: wave w owns 8
// n-tiles (4 gates x 2 halves) of hidden slice [32w,32w+32); lane updates
// jsel = wbase + 16*sel + col.
//
// Verified structure: RAW barrier with lgkmcnt(1) + pre-barrier A0c read
// (R8), k-tile slot permutation + deferred ring write (R7), 4 waves /
// 1-per-SIMD (R5: 8w regresses), exp2-prescaled weights + sign-folded fma
// tails (R2-R6), Z-seeded accumulators, in-place xg reload (R6), LDS hs
// ring instead of per-step global store (R4: vmcnt in-order retire
// entanglement), one-time B-fragment launder, waves_per_eu(1,1).
// ---------------------------------------------------------------------------
__global__
__attribute__((amdgpu_flat_work_group_size(256, 256), amdgpu_waves_per_eu(1, 1)))
void scan_kernel(
    const _Float16* __restrict__ Wp,
    const float* __restrict__ xgp,
    float* __restrict__ hs)
{
    const int tid  = threadIdx.x;
    const int lane = tid & 63;
    const int w    = tid >> 6;        // wave id 0..3
    const int col  = lane & 15;
    const int quad = lane >> 4;
    const int wbase = w * 32;
    const bool sel  = (lane >= 32);
    const int jsel  = wbase + (sel ? 16 : 0) + col; // hidden index this lane updates
    const int aoff  = quad * 8;

    // element offsets of A-fragment slots 0..3 (slot s = k-tile (w+s)&3)
    const int offA0 = ((w + 0) & 3) * 32 + aoff;   // own slice
    const int offA1 = ((w + 1) & 3) * 32 + aoff;
    const int offA2 = ((w + 2) & 3) * 32 + aoff;
    const int offA3 = ((w + 3) & 3) * 32 + aoff;

    __shared__ __align__(16) _Float16 h_lds[2][HH];          // 512 B
    __shared__ __align__(16) float hs_l[BB * HH];            // 128 KB ring

    // ---- B-fragments: slot s holds W k-tile (w+s)&3 (runtime remap) ----
#define BLOADP(nt, s) \
    half8 B##nt##_##s = *(const half8*)(Wp + (((w * 32 + (nt) * 4 + ((w + (s)) & 3)) * 64 + lane) * 8));
#define FOR_KT(X, nt) X(nt, 0) X(nt, 1) X(nt, 2) X(nt, 3)
#define FOR_NT(X) FOR_KT(X, 0) FOR_KT(X, 1) FOR_KT(X, 2) FOR_KT(X, 3) \
                  FOR_KT(X, 4) FOR_KT(X, 5) FOR_KT(X, 6) FOR_KT(X, 7)
    FOR_NT(BLOADP)

    // ---- ONE-TIME launder: opaque-define the fragments (cannot be sunk) ----
    asm volatile("" : "+v"(B0_0), "+v"(B0_1), "+v"(B0_2), "+v"(B0_3),
                      "+v"(B1_0), "+v"(B1_1), "+v"(B1_2), "+v"(B1_3),
                      "+v"(B2_0), "+v"(B2_1), "+v"(B2_2), "+v"(B2_3),
                      "+v"(B3_0), "+v"(B3_1), "+v"(B3_2), "+v"(B3_3));
    asm volatile("" : "+v"(B4_0), "+v"(B4_1), "+v"(B4_2), "+v"(B4_3),
                      "+v"(B5_0), "+v"(B5_1), "+v"(B5_2), "+v"(B5_3),
                      "+v"(B6_0), "+v"(B6_1), "+v"(B6_2), "+v"(B6_3),
                      "+v"(B7_0), "+v"(B7_1), "+v"(B7_2), "+v"(B7_3));

    if (tid < HH) h_lds[0][tid] = (_Float16)0.f;

    // persistent zero accumulator seed (4 VGPRs, laundered so it is never
    // rematerialized as per-step v_movs)
    f32x4 Z = {0.f, 0.f, 0.f, 0.f};
    asm volatile("" : "+v"(Z));

    // 2-deep register prefetch of the packed gate biases (16 B/lane)
    const float* __restrict__ xgl = xgp + jsel * 4;
    f32x4 xg0 = *(const f32x4*)(xgl + 0 * GG);
    f32x4 xg1 = *(const f32x4*)(xgl + 1 * GG);

    float c = 0.f;          // in 2*log2e-scaled units
    float hval_prev = 0.f;  // deferred hs_l ring write (one step behind)
    __syncthreads();        // h_lds[0] init visible; drains prologue loads

    // carried A0 (own slice of h_lds[0]) for step 0
    half8 A0c = *(const half8*)(&h_lds[0][0] + offA0);

#define MM(a, b, cc) __builtin_amdgcn_mfma_f32_16x16x32_f16((a), (b), (cc), 0, 0, 0)
#define STEP(par, XCUR) do {                                                            \
    const int t = t2 + (par);                                                           \
    const _Float16* hl = h_lds[(par)];                                                  \
    half8 A0 = A0c;                                                                     \
    half8 A1 = *(const half8*)(hl + offA1);                                             \
    half8 A2 = *(const half8*)(hl + offA2);                                             \
    half8 A3 = *(const half8*)(hl + offA3);                                             \
    /* deferred ring write of h_{t-1}: unconditional (dup lanes, same val), */          \
    /* fenced so it issues early and retires under the MFMAs               */           \
    hs_l[((t - 1) & (BB - 1)) * HH + jsel] = hval_prev;                                 \
    asm volatile("" ::: "memory");                                                      \
    f32x4 C0, C1, C2, C3, C4, C5, C6, C7;                                               \
    C4 = MM(A0, B4_0, Z);  C5 = MM(A0, B5_0, Z);  C0 = MM(A0, B0_0, Z);                 \
    C1 = MM(A0, B1_0, Z);  C2 = MM(A0, B2_0, Z);  C3 = MM(A0, B3_0, Z);                 \
    C6 = MM(A0, B6_0, Z);  C7 = MM(A0, B7_0, Z);                                        \
    C4 = MM(A1, B4_1, C4); C5 = MM(A1, B5_1, C5); C0 = MM(A1, B0_1, C0);                \
    C1 = MM(A1, B1_1, C1); C2 = MM(A1, B2_1, C2); C3 = MM(A1, B3_1, C3);                \
    C6 = MM(A1, B6_1, C6); C7 = MM(A1, B7_1, C7);                                       \
    C4 = MM(A2, B4_2, C4); C5 = MM(A2, B5_2, C5); C0 = MM(A2, B0_2, C0);                \
    C1 = MM(A2, B1_2, C1); C2 = MM(A2, B2_2, C2); C3 = MM(A2, B3_2, C3);                \
    C6 = MM(A2, B6_2, C6); C7 = MM(A2, B7_2, C7);                                       \
    C4 = MM(A3, B4_3, C4); C5 = MM(A3, B5_3, C5); C0 = MM(A3, B0_3, C0);                \
    C1 = MM(A3, B1_3, C1); C2 = MM(A3, B2_3, C2); C3 = MM(A3, B3_3, C3);                \
    C6 = MM(A3, B6_3, C6); C7 = MM(A3, B7_3, C7);                                       \
    /* pre-activations (exp2-prescaled): pg by 2log2e, others by log2e */               \
    float pi = (sel ? C1[0] : C0[0]) + (XCUR).x;                                        \
    float pf = (sel ? C3[0] : C2[0]) + (XCUR).y;                                        \
    float pg = (sel ? C5[0] : C4[0]) + (XCUR).z;                                        \
    float po = (sel ? C7[0] : C6[0]) + (XCUR).w;                                        \
    /* in-place reload AFTER last use (R6: fully hidden at 2-step depth) */             \
    (XCUR) = *(const f32x4*)(xgl + ((t + 2) & (TT - 1)) * GG);                          \
    float iv = __builtin_amdgcn_rcpf(1.0f + __builtin_amdgcn_exp2f(-pi));               \
    float fv = __builtin_amdgcn_rcpf(1.0f + __builtin_amdgcn_exp2f(-pf));               \
    float ov = __builtin_amdgcn_rcpf(1.0f + __builtin_amdgcn_exp2f(-po));               \
    float Eg = __builtin_amdgcn_exp2f(fabsf(pg));                                       \
    float rg = __builtin_amdgcn_rcpf(Eg + 1.0f);                                        \
    float T  = copysignf(TWOLOG2E, pg);                                                 \
    float gvs = fmaf(-2.0f * T, rg, T);  /* = 2log2e * tanh(raw_g) */                   \
    c = fmaf(fv, c, iv * gvs);           /* c stays in 2log2e-scaled units */           \
    float Ec = __builtin_amdgcn_exp2f(fabsf(c));                                        \
    float rc = __builtin_amdgcn_rcpf(Ec + 1.0f);                                        \
    float Ao = copysignf(ov, c);                                                        \
    float hval = fmaf(-2.0f * Ao, rc, Ao);                                              \
    h_lds[1 - (par)][jsel] = (_Float16)hval;   /* unconditional (dup-safe) */           \
    hval_prev = hval;                                                                   \
    asm volatile("" ::: "memory");             /* order: h write < A0c read */          \
    /* pre-barrier prefetch of next step's A0 = own slice, just written.    */          \
    /* lgkmcnt(1): DS retires in order -> h_write done, A0c read stays in   */          \
    /* flight across the barrier (latency overlaps wait+barrier).           */          \
    A0c = *(const half8*)(&h_lds[1 - (par)][0] + offA0);                                \
    asm volatile("s_waitcnt lgkmcnt(1)\n\ts_barrier" ::: "memory");                     \
} while (0)

    for (int t2 = 0; t2 < TT; t2 += 2) {
        STEP(0, xg0);   // reads h_lds[0], writes h_lds[1]
        STEP(1, xg1);   // reads h_lds[1], writes h_lds[0]
    }
#undef STEP
#undef MM

    // final deferred ring write: h_511 -> slot 255
    hs_l[(BB - 1) * HH + jsel] = hval_prev;
    __syncthreads();

    // dump hs ring (128 KB LDS -> global, coalesced)
    const f32x4* s = (const f32x4*)hs_l;
    f32x4* d = (f32x4*)hs;
#pragma unroll 4
    for (int i = tid; i < BB * HH / 4; i += 256) d[i] = s[i];
}

// ---------------------------------------------------------------------------
// Kernel 3: out[r,:] = W2 @ (W1 @ hs[r] + b1) + b2  (no activation in ref)
//
// R9: register-blocking over rows. Old kernel: one block per row -> every
// block re-read W1+W2 (96 KB; 24 MB across 256 blocks). Now each block
// handles 8 rows; W row chunks loaded once and applied to 8 staged h-rows.
// W traffic /8; grid 256 -> 32 blocks. Per-row accumulation structure
// (single running acc) preserved.
// ---------------------------------------------------------------------------
__global__ __launch_bounds__(128) void mlp_kernel(
    const float* __restrict__ hs,
    const float* __restrict__ W1,
    const float* __restrict__ b1,
    const float* __restrict__ W2,
    const float* __restrict__ b2,
    float* __restrict__ out)
{
    const int r0 = blockIdx.x * RI;
    const int j  = threadIdx.x;

    __shared__ __align__(16) float hsh[RI][HH];   // 4 KB: 8 h-rows
    __shared__ __align__(16) float z[RI][HH];     // 4 KB: 8 z-rows

    {
        const float4* src = (const float4*)(hs + (size_t)r0 * HH);
        float4* dst = (float4*)&hsh[0][0];
        for (int i = j; i < RI * HH / 4; i += 128) dst[i] = src[i];
    }
    __syncthreads();

    {
        const float4* __restrict__ wrow = (const float4*)(W1 + j * HH);
        float acc[RI];
#pragma unroll
        for (int r = 0; r < RI; r++) acc[r] = b1[j];
#pragma unroll 8
        for (int i = 0; i < 32; i++) {
            const float4 ww = wrow[i];        // W1 chunk loaded ONCE, used 8x
#pragma unroll
            for (int r = 0; r < RI; r++) {
                const float4 h = ((const float4*)&hsh[r][0])[i];
                acc[r] += ww.x * h.x + ww.y * h.y + ww.z * h.z + ww.w * h.w;
            }
        }
#pragma unroll
        for (int r = 0; r < RI; r++) z[r][j] = acc[r];
    }
    __syncthreads();

    if (j < OO) {
        const float4* __restrict__ wrow = (const float4*)(W2 + j * HH);
        float acc[RI];
#pragma unroll
        for (int r = 0; r < RI; r++) acc[r] = b2[j];
#pragma unroll 8
        for (int i = 0; i < 32; i++) {
            const float4 ww = wrow[i];        // W2 chunk loaded ONCE, used 8x
#pragma unroll
            for (int r = 0; r < RI; r++) {
                const float4 zz = ((const float4*)&z[r][0])[i];
                acc[r] += ww.x * zz.x + ww.y * zz.y + ww.z * zz.z + ww.w * zz.w;
            }
        }
#pragma unroll
        for (int r = 0; r < RI; r++) out[(r0 + r) * OO + j] = acc[r];
    }
}

// ---------------------------------------------------------------------------
// Launch. Inputs: 0:x 1:W_ih 2:W_hh 3:b_ih 4:b_hh 5:W1 6:b1 7:W2 8:b2
// ws: xg packed (1 MB) | hs (128 KB) | Wp packed f16 frags (128 KB)
// ---------------------------------------------------------------------------
extern "C" void kernel_launch(void* const* d_in, const int* in_sizes, int n_in,
                              void* d_out, int out_size, void* d_ws, size_t ws_size,
                              hipStream_t stream) {
    const float* x    = (const float*)d_in[0];
    const float* W_ih = (const float*)d_in[1];
    const float* W_hh = (const float*)d_in[2];
    const float* b_ih = (const float*)d_in[3];
    const float* b_hh = (const float*)d_in[4];
    const float* W1   = (const float*)d_in[5];
    const float* b1   = (const float*)d_in[6];
    const float* W2   = (const float*)d_in[7];
    const float* b2   = (const float*)d_in[8];
    float* out = (float*)d_out;

    float*    xg = (float*)d_ws;                 // T*4H   = 262144 f32 (packed)
    float*    hs = xg + TT * GG;                 // 256*H  =  32768 f32
    _Float16* Wp = (_Float16*)(hs + BB * HH);    // 4H*H   =  65536 f16 (packed frags)

    xgpack_kernel<<<TT / TI + 16, 512, 0, stream>>>(x, W_ih, b_ih, b_hh, W_hh, xg, Wp);
    scan_kernel<<<1, 256, 0, stream>>>(Wp, xg, hs);
    mlp_kernel<<<BB / RI, 128, 0, stream>>>(hs, W1, b1, W2, b2, out);
}